// Round 6
// baseline (184.982 us; speedup 1.0000x reference)
//
#include <hip/hip_runtime.h>
#include <hip/hip_bf16.h>

typedef unsigned short u16;
typedef unsigned int u32;
typedef __attribute__((ext_vector_type(8))) short short8;
typedef __attribute__((ext_vector_type(4))) float f32x4;
typedef __attribute__((ext_vector_type(16))) float f32x16;

#define VMW(n) asm volatile("s_waitcnt vmcnt(" #n ")" ::: "memory")
#define BARRIER() do { asm volatile("" ::: "memory"); __builtin_amdgcn_s_barrier(); } while (0)

__device__ __forceinline__ u16 f2bf(float f) {
    union { float f; unsigned int u; } v; v.f = f;
    unsigned int u = v.u;
    return (u16)((u + 0x7FFFu + ((u >> 16) & 1u)) >> 16);
}
__device__ __forceinline__ u32 pk2(float a, float b) {
    return ((u32)f2bf(b) << 16) | (u32)f2bf(a);
}
__device__ __forceinline__ void gload_lds16(const u16* g, u16* l) {
    __builtin_amdgcn_global_load_lds((const __attribute__((address_space(1))) void*)g,
                                     (__attribute__((address_space(3))) void*)l, 16, 0, 0);
}

// ---------------- prep: fp32 -> bf16 (vectorized) ----------------
__global__ void k_convert(const float* __restrict__ x, u16* __restrict__ o, int n4) {
    int i = blockIdx.x * blockDim.x + threadIdx.x;
    if (i < n4) {
        float4 v = ((const float4*)x)[i];
        ushort4 r;
        r.x = f2bf(v.x); r.y = f2bf(v.y); r.z = f2bf(v.z); r.w = f2bf(v.w);
        ((ushort4*)o)[i] = r;
    }
}

// ---------------- prep: W [K][N] fp32 -> Wt [N][K] bf16 ----------------
__global__ void k_transpose_bf(const float* __restrict__ W, u16* __restrict__ Wt, int K, int N) {
    __shared__ u16 t[32][33];
    int n0 = blockIdx.x * 32, k0 = blockIdx.y * 32;
    int tx = threadIdx.x, ty = threadIdx.y;
    #pragma unroll
    for (int i = 0; i < 4; i++) {
        t[ty + i * 8][tx] = f2bf(W[(long)(k0 + ty + i * 8) * N + n0 + tx]);
    }
    __syncthreads();
    #pragma unroll
    for (int i = 0; i < 4; i++) {
        Wt[(long)(n0 + ty + i * 8) * K + k0 + tx] = t[tx][ty + i * 8];
    }
}

// ---------------- bf16 MFMA GEMM v3: 8-wave 128x256 tile, BK=32, ring-3 LDS ----------------
// Pipeline: stage K-tile j+2 issued BEFORE compute of j; counted VMW(3) (never 0
// in-loop) guarantees j+1 landed; ONE barrier per K-tile (slot (j+2)%3 was last
// read at iter j-1, whose end-barrier precedes this stage -> WAR safe).
// LDS packing: 2 global rows per LDS row ([64][64] A, [128][64] B), chunk
// swizzle ((ln&1)*4+gp)^((ln>>1)&7) -> uniform 8 words/bank (b128 floor).
// Stage source pre-swizzled to match (both-sides rule). Requires K%64==0.
template<int EPI>
__global__ __launch_bounds__(512, 4) void k_gemm8(
    const u16* __restrict__ A, const u16* __restrict__ Bt, const float* __restrict__ bias,
    float* __restrict__ Cf, u16* __restrict__ q_out, u16* __restrict__ k_out, u16* __restrict__ vt_out,
    int M, int N, int K, int mtiles)
{
    __shared__ u16 sA[3][4096];   // [slot][64 lds-rows x 64]  = 128 M-rows x 32 k
    __shared__ u16 sB[3][8192];   // [slot][128 lds-rows x 64] = 256 N-rows x 32 k
    int tid = threadIdx.x;
    int w = tid >> 6, lane = tid & 63;
    int wm = w >> 2, wn = w & 3;
    int ln = lane & 15, gp = lane >> 4;

    // XCD-aware bijective swizzle (gridDim.x % 8 == 0)
    int cpx = gridDim.x >> 3;
    int bid = blockIdx.x;
    int wgid = (bid & 7) * cpx + (bid >> 3);
    int mt = wgid % mtiles, nt = wgid / mtiles;
    int gm0 = mt * 128, gn0 = nt * 256;

    // staging: lane l writes LDS (row = w*8 + (l>>3), chunk = l&7); that slot
    // must hold global chunk cu = (l&7) ^ (row&7); global row = 2*lds_row + (cu>>2).
    int cu = (lane & 7) ^ ((lane >> 3) & 7);
    int srl = w * 8 + (lane >> 3);
    const u16* aS  = A  + (size_t)(gm0 + 2 * srl + (cu >> 2)) * K + (cu & 3) * 8;
    const u16* bS0 = Bt + (size_t)(gn0 + 2 * srl + (cu >> 2)) * K + (cu & 3) * 8;
    const u16* bS1 = bS0 + (size_t)128 * K;   // N-rows 128..255 -> lds rows 64..127

    auto stage = [&](int j) {
        int sl = j % 3;
        int ko = j << 5;
        gload_lds16(aS + ko,  &sA[sl][w * 512]);
        gload_lds16(bS0 + ko, &sB[sl][w * 512]);
        gload_lds16(bS1 + ko, &sB[sl][4096 + w * 512]);
    };

    // fragment reads: global row = frag + ln -> lds row = base + (ln>>1),
    // col = (ln&1)*32 + gp*8 -> chunk = ((ln&1)*4+gp) ^ ((ln>>1)&7) (fi/fj-invariant)
    int chunk = (((ln & 1) << 2) + gp) ^ ((ln >> 1) & 7);
    int aoff = (wm * 32 + (ln >> 1)) * 64 + chunk * 8;   // + fi*512
    int boff = (wn * 32 + (ln >> 1)) * 64 + chunk * 8;   // + fj*512

    f32x4 zf = {0.f, 0.f, 0.f, 0.f};
    f32x4 acc[4][4];
    #pragma unroll
    for (int i = 0; i < 4; i++)
        #pragma unroll
        for (int j = 0; j < 4; j++) acc[i][j] = zf;

    int nk = K >> 5;                       // 24 for K=768
    stage(0); stage(1);
    VMW(3);                                // K-tile 0 landed; stage(1) in flight
    BARRIER();
    #pragma unroll 3
    for (int j = 0; j < nk; ++j) {
        int sl = j % 3;
        if (j + 2 < nk) stage(j + 2);      // issue BEFORE compute (T3 recipe)
        short8 af[4], bf8[4];
        #pragma unroll
        for (int i = 0; i < 4; i++) af[i]  = *(const short8*)&sA[sl][aoff + i * 512];
        #pragma unroll
        for (int i = 0; i < 4; i++) bf8[i] = *(const short8*)&sB[sl][boff + i * 512];
        __builtin_amdgcn_s_setprio(1);
        #pragma unroll
        for (int i = 0; i < 4; i++)
            #pragma unroll
            for (int jj = 0; jj < 4; jj++)
                acc[i][jj] = __builtin_amdgcn_mfma_f32_16x16x32_bf16(af[i], bf8[jj], acc[i][jj], 0, 0, 0);
        __builtin_amdgcn_s_setprio(0);
        if (j + 2 < nk) { VMW(3); }        // K-tile j+1 landed; j+2 stays in flight
        else if (j + 1 < nk) { VMW(0); }   // tail drain (once)
        BARRIER();
    }

    #pragma unroll
    for (int i = 0; i < 4; i++) {
        #pragma unroll
        for (int j = 0; j < 4; j++) {
            #pragma unroll
            for (int r = 0; r < 4; r++) {
                int m = gm0 + wm * 64 + i * 16 + gp * 4 + r;
                int n = gn0 + wn * 64 + j * 16 + ln;
                float v = acc[i][j][r] + bias[n];
                if (EPI == 0) {
                    Cf[(long)m * N + n] = v;
                } else {
                    int b = m >> 10, t = m & 1023;
                    int which = n / 768, c = n % 768;
                    int h = c >> 6, d = c & 63;
                    int bh = b * 12 + h;
                    u16 bv = f2bf(v);
                    if (which == 0)      q_out[((long)bh * 1024 + t) * 64 + d] = bv;
                    else if (which == 1) k_out[((long)bh * 1024 + t) * 64 + d] = bv;
                    else                 vt_out[((long)bh * 64 + d) * 1024 + t] = bv;
                }
            }
        }
    }
}

// ---------------- causal flash attention v2: swapped 32x32 MFMA, in-register softmax ----------------
// Q,K: [BH][T][64] bf16 ; Vt: [BH][64][T] bf16 ; O: [B][T][768] bf16
__global__ __launch_bounds__(256) void k_attn(
    const u16* __restrict__ Q, const u16* __restrict__ Kb, const u16* __restrict__ Vt,
    u16* __restrict__ O)
{
    int tid = threadIdx.x, w = tid >> 6, lane = tid & 63;
    int l31 = lane & 31, hi = lane >> 5;
    int bx = blockIdx.x;
    int g = bx / 96, bh = bx - g * 96;          // g in 0..7, bh in 0..95
    int qt = g + 8 * w, q0 = qt * 32;           // wave's q-tile (work-balanced)
    int b = bh / 12, h = bh - b * 12;
    const u16* Qb  = Q  + (size_t)bh * 65536;
    const u16* Kbb = Kb + (size_t)bh * 65536;
    const u16* Vb  = Vt + (size_t)bh * 65536;

    short8 qf[4];
    #pragma unroll
    for (int ch = 0; ch < 4; ch++)
        qf[ch] = *(const short8*)&Qb[(q0 + l31) * 64 + ch * 16 + hi * 8];

    f32x16 o0 = {}, o1 = {};
    float mrun = -INFINITY, lsum = 0.f;
    const float SC = 0.18033688011f;            // 0.125 * log2(e)

    int nit = qt + 1;
    for (int it = 0; it < nit; it++) {
        int kt = it * 32;
        f32x16 s = {};
        #pragma unroll
        for (int ch = 0; ch < 4; ch++) {
            short8 kf = *(const short8*)&Kbb[(kt + l31) * 64 + ch * 16 + hi * 8];
            s = __builtin_amdgcn_mfma_f32_32x32x16_bf16(kf, qf[ch], s, 0, 0, 0);
        }
        float ps[16];
        int qg = q0 + l31;
        #pragma unroll
        for (int r = 0; r < 16; r++) {
            int krow = kt + (r & 3) + 8 * (r >> 2) + 4 * hi;
            ps[r] = (krow <= qg) ? s[r] * SC : -1e30f;
        }
        float t8[8];
        #pragma unroll
        for (int i = 0; i < 8; i++) t8[i] = fmaxf(ps[i], ps[i + 8]);
        float t4a = fmaxf(t8[0], t8[1]), t4b = fmaxf(t8[2], t8[3]);
        float t4c = fmaxf(t8[4], t8[5]), t4d = fmaxf(t8[6], t8[7]);
        float tm = fmaxf(fmaxf(t4a, t4b), fmaxf(t4c, t4d));
        tm = fmaxf(tm, __shfl_xor(tm, 32));
        float mn = fmaxf(mrun, tm);
        float scale = exp2f(mrun - mn);
        mrun = mn;
        float rs = 0.f;
        #pragma unroll
        for (int r = 0; r < 16; r++) { ps[r] = exp2f(ps[r] - mn); rs += ps[r]; }
        rs += __shfl_xor(rs, 32);
        lsum = lsum * scale + rs;
        #pragma unroll
        for (int r = 0; r < 16; r++) { o0[r] *= scale; o1[r] *= scale; }
        u32 c[8], sw[8];
        #pragma unroll
        for (int i = 0; i < 8; i++) c[i] = pk2(ps[2 * i], ps[2 * i + 1]);
        #pragma unroll
        for (int i = 0; i < 8; i++) sw[i] = (u32)__shfl_xor((int)c[i], 32);
        union { u32 u[4]; short8 s8; } pb0, pb1;
        pb0.u[0] = hi ? sw[2] : c[0];
        pb0.u[1] = hi ? sw[3] : c[1];
        pb0.u[2] = hi ? c[2]  : sw[0];
        pb0.u[3] = hi ? c[3]  : sw[1];
        pb1.u[0] = hi ? sw[6] : c[4];
        pb1.u[1] = hi ? sw[7] : c[5];
        pb1.u[2] = hi ? c[6]  : sw[4];
        pb1.u[3] = hi ? c[7]  : sw[5];
        #pragma unroll
        for (int kh = 0; kh < 2; kh++) {
            const short8* pbp = kh ? &pb1.s8 : &pb0.s8;
            short8 vf0 = *(const short8*)&Vb[(size_t)l31 * 1024 + kt + kh * 16 + hi * 8];
            short8 vf1 = *(const short8*)&Vb[(size_t)(32 + l31) * 1024 + kt + kh * 16 + hi * 8];
            o0 = __builtin_amdgcn_mfma_f32_32x32x16_bf16(vf0, *pbp, o0, 0, 0, 0);
            o1 = __builtin_amdgcn_mfma_f32_32x32x16_bf16(vf1, *pbp, o1, 0, 0, 0);
        }
    }

    float inv = 1.0f / lsum;
    int t = q0 + l31;
    size_t base = ((size_t)(b * 1024 + t)) * 768 + h * 64;
    #pragma unroll
    for (int rq = 0; rq < 4; rq++) {
        ushort4 u0, u1;
        u0.x = f2bf(o0[4 * rq + 0] * inv); u0.y = f2bf(o0[4 * rq + 1] * inv);
        u0.z = f2bf(o0[4 * rq + 2] * inv); u0.w = f2bf(o0[4 * rq + 3] * inv);
        u1.x = f2bf(o1[4 * rq + 0] * inv); u1.y = f2bf(o1[4 * rq + 1] * inv);
        u1.z = f2bf(o1[4 * rq + 2] * inv); u1.w = f2bf(o1[4 * rq + 3] * inv);
        *(ushort4*)&O[base + rq * 8 + hi * 4]      = u0;
        *(ushort4*)&O[base + 32 + rq * 8 + hi * 4] = u1;
    }
}

extern "C" void kernel_launch(void* const* d_in, const int* in_sizes, int n_in,
                              void* d_out, int out_size, void* d_ws, size_t ws_size,
                              hipStream_t stream)
{
    const float* x     = (const float*)d_in[0];
    const float* W_qkv = (const float*)d_in[1];
    const float* b_qkv = (const float*)d_in[2];
    const float* W_out = (const float*)d_in[3];
    const float* b_out = (const float*)d_in[4];
    float* out = (float*)d_out;

    char* w = (char*)d_ws;
    u16* xb  = (u16*)w; w += (size_t)8192 * 768 * 2;
    u16* wqt = (u16*)w; w += (size_t)2304 * 768 * 2;
    u16* wot = (u16*)w; w += (size_t)768 * 768 * 2;
    u16* qb  = (u16*)w; w += (size_t)96 * 1024 * 64 * 2;
    u16* kb  = (u16*)w; w += (size_t)96 * 1024 * 64 * 2;
    u16* vt  = (u16*)w; w += (size_t)96 * 64 * 1024 * 2;
    u16* ao  = (u16*)w; w += (size_t)8192 * 768 * 2;

    k_convert<<<dim3(6144), 256, 0, stream>>>(x, xb, 1572864);
    k_transpose_bf<<<dim3(72, 24), dim3(32, 8), 0, stream>>>(W_qkv, wqt, 768, 2304);
    k_transpose_bf<<<dim3(24, 24), dim3(32, 8), 0, stream>>>(W_out, wot, 768, 768);
    k_gemm8<1><<<dim3(576), 512, 0, stream>>>(xb, wqt, b_qkv, nullptr, qb, kb, vt, 8192, 2304, 768, 64);
    k_attn<<<dim3(768), 256, 0, stream>>>(qb, kb, vt, ao);
    k_gemm8<0><<<dim3(192), 512, 0, stream>>>(ao, wot, b_out, out, nullptr, nullptr, nullptr, 8192, 768, 768, 64);
}

// Round 7
// 169.184 us; speedup vs baseline: 1.0934x; 1.0934x over previous
//
#include <hip/hip_runtime.h>
#include <hip/hip_bf16.h>

typedef unsigned short u16;
typedef unsigned int u32;
typedef __attribute__((ext_vector_type(8))) short short8;
typedef __attribute__((ext_vector_type(4))) float f32x4;
typedef __attribute__((ext_vector_type(16))) float f32x16;

#define VMW(n) asm volatile("s_waitcnt vmcnt(" #n ")" ::: "memory")
#define BARRIER() do { asm volatile("" ::: "memory"); __builtin_amdgcn_s_barrier(); } while (0)

__device__ __forceinline__ u16 f2bf(float f) {
    union { float f; unsigned int u; } v; v.f = f;
    unsigned int u = v.u;
    return (u16)((u + 0x7FFFu + ((u >> 16) & 1u)) >> 16);
}
__device__ __forceinline__ u32 pk2(float a, float b) {
    return ((u32)f2bf(b) << 16) | (u32)f2bf(a);
}
__device__ __forceinline__ void gload_lds16(const u16* g, u16* l) {
    __builtin_amdgcn_global_load_lds((const __attribute__((address_space(1))) void*)g,
                                     (__attribute__((address_space(3))) void*)l, 16, 0, 0);
}

// ---------------- prep: fp32 -> bf16 (vectorized) ----------------
__global__ void k_convert(const float* __restrict__ x, u16* __restrict__ o, int n4) {
    int i = blockIdx.x * blockDim.x + threadIdx.x;
    if (i < n4) {
        float4 v = ((const float4*)x)[i];
        ushort4 r;
        r.x = f2bf(v.x); r.y = f2bf(v.y); r.z = f2bf(v.z); r.w = f2bf(v.w);
        ((ushort4*)o)[i] = r;
    }
}

// ---------------- prep: W [K][N] fp32 -> Wt [N][K] bf16 ----------------
__global__ void k_transpose_bf(const float* __restrict__ W, u16* __restrict__ Wt, int K, int N) {
    __shared__ u16 t[32][33];
    int n0 = blockIdx.x * 32, k0 = blockIdx.y * 32;
    int tx = threadIdx.x, ty = threadIdx.y;
    #pragma unroll
    for (int i = 0; i < 4; i++) {
        t[ty + i * 8][tx] = f2bf(W[(long)(k0 + ty + i * 8) * N + n0 + tx]);
    }
    __syncthreads();
    #pragma unroll
    for (int i = 0; i < 4; i++) {
        Wt[(long)(n0 + ty + i * 8) * K + k0 + tx] = t[tx][ty + i * 8];
    }
}

// ---------------- bf16 MFMA GEMM v4: BM=128 BN=256 BK=64, 8 waves, 32x32x16 ----------------
// Ring-3 LDS (48KB/slot), stage(j+2) at iter top, counted VMW(6) (never 0 in
// main loop), ONE barrier per K-tile. Per K-tile: 4 phases, phase p = {ds_read
// k-sub p+1 || 4x mfma_32x32x16 of k-sub p} -> reads lead MFMAs by one phase.
// Chunk swizzle: LDS slot (row, s) holds global 16B-chunk s ^ (row&7), applied
// on BOTH stage-source and ds_read (rule #21). Requires K % 192 == 0 (unroll 3).
template<int EPI>
__global__ __launch_bounds__(512, 2) void k_gemm8p(
    const u16* __restrict__ A, const u16* __restrict__ Bt, const float* __restrict__ bias,
    float* __restrict__ Cf, u16* __restrict__ q_out, u16* __restrict__ k_out, u16* __restrict__ vt_out,
    int M, int N, int K)
{
    __shared__ u16 sA[3][8192];    // 128 rows x 64 k (row = 128B = 8 chunks of 16B)
    __shared__ u16 sB[3][16384];   // 256 rows x 64 k
    int tid = threadIdx.x;
    int w = tid >> 6, lane = tid & 63;
    int wm = w >> 2, wn = w & 3;           // 2 x 4 waves, wave out = 64x64
    int l31 = lane & 31, hi = lane >> 5;
    int gm0 = blockIdx.x * 128, gn0 = blockIdx.y * 256;

    // staging: call q covers tile-rows (q*8+w)*8 .. +7; lane l -> row +(l>>3),
    // LDS chunk (l&7) holds global chunk g = (l&7) ^ ((l>>3)&7)  (row&7 = (l>>3)&7).
    int g = (lane & 7) ^ ((lane >> 3) & 7);
    const u16* Ag = A  + (size_t)(gm0 + (lane >> 3)) * K + g * 8;
    const u16* Bg = Bt + (size_t)(gn0 + (lane >> 3)) * K + g * 8;

    auto stage = [&](int j) {
        int sl = j % 3;
        size_t ko = (size_t)j << 6;
        #pragma unroll
        for (int q = 0; q < 2; q++)
            gload_lds16(Ag + ko + (size_t)(q * 8 + w) * 8 * K, &sA[sl][(q * 8 + w) * 512]);
        #pragma unroll
        for (int q = 0; q < 4; q++)
            gload_lds16(Bg + ko + (size_t)(q * 8 + w) * 8 * K, &sB[sl][(q * 8 + w) * 512]);
    };

    f32x16 acc[2][2] = {};

    // frag read: row = base + l31 (base % 32 == 0 -> row&7 = l31&7), k-sub ks:
    // chunk c = ks*2 + hi, lds chunk = c ^ (l31&7).
    int swl = l31 & 7;
    int arow0 = (wm * 64 + l31) * 64, arow1 = (wm * 64 + 32 + l31) * 64;
    int brow0 = (wn * 64 + l31) * 64, brow1 = (wn * 64 + 32 + l31) * 64;

#define RD4(sl, ks, aa, bb) do {                                            \
    int cc = (((ks) * 2 + hi) ^ swl) * 8;                                   \
    aa[0] = *(const short8*)&sA[sl][arow0 + cc];                            \
    aa[1] = *(const short8*)&sA[sl][arow1 + cc];                            \
    bb[0] = *(const short8*)&sB[sl][brow0 + cc];                            \
    bb[1] = *(const short8*)&sB[sl][brow1 + cc];                            \
} while (0)
#define MM4(aa, bb) do {                                                    \
    __builtin_amdgcn_s_setprio(1);                                          \
    acc[0][0] = __builtin_amdgcn_mfma_f32_32x32x16_bf16(aa[0], bb[0], acc[0][0], 0, 0, 0); \
    acc[0][1] = __builtin_amdgcn_mfma_f32_32x32x16_bf16(aa[0], bb[1], acc[0][1], 0, 0, 0); \
    acc[1][0] = __builtin_amdgcn_mfma_f32_32x32x16_bf16(aa[1], bb[0], acc[1][0], 0, 0, 0); \
    acc[1][1] = __builtin_amdgcn_mfma_f32_32x32x16_bf16(aa[1], bb[1], acc[1][1], 0, 0, 0); \
    __builtin_amdgcn_s_setprio(0);                                          \
} while (0)

    int nk = K >> 6;                       // 12 for K=768
    stage(0); stage(1);
    VMW(6);                                // slot0 landed; stage(1) in flight
    BARRIER();
    #pragma unroll 3
    for (int j = 0; j < nk; ++j) {
        int sl = j % 3;
        if (j + 2 < nk) stage(j + 2);      // ring-3: WAR-safe (last read iter j-1)
        short8 aP[2], bP[2], aQ[2], bQ[2];
        RD4(sl, 0, aP, bP);
        RD4(sl, 1, aQ, bQ); MM4(aP, bP);
        RD4(sl, 2, aP, bP); MM4(aQ, bQ);
        RD4(sl, 3, aQ, bQ); MM4(aP, bP);
        MM4(aQ, bQ);
        if (j + 2 < nk) { VMW(6); }        // stage(j+1) landed; j+2 stays in flight
        else if (j + 1 < nk) { VMW(0); }   // tail drain (once)
        BARRIER();
    }
#undef RD4
#undef MM4

    #pragma unroll
    for (int fi = 0; fi < 2; fi++) {
        #pragma unroll
        for (int fj = 0; fj < 2; fj++) {
            #pragma unroll
            for (int r = 0; r < 16; r++) {
                int m = gm0 + wm * 64 + fi * 32 + (r & 3) + 8 * (r >> 2) + 4 * hi;
                int n = gn0 + wn * 64 + fj * 32 + l31;
                float v = acc[fi][fj][r] + bias[n];
                if (EPI == 0) {
                    Cf[(long)m * N + n] = v;
                } else {
                    int b = m >> 10, t = m & 1023;
                    int which = n / 768, c = n % 768;
                    int h = c >> 6, d = c & 63;
                    int bh = b * 12 + h;
                    u16 bv = f2bf(v);
                    if (which == 0)      q_out[((long)bh * 1024 + t) * 64 + d] = bv;
                    else if (which == 1) k_out[((long)bh * 1024 + t) * 64 + d] = bv;
                    else                 vt_out[((long)bh * 64 + d) * 1024 + t] = bv;
                }
            }
        }
    }
}

// ---------------- causal flash attention v2: swapped 32x32 MFMA, in-register softmax ----------------
// Q,K: [BH][T][64] bf16 ; Vt: [BH][64][T] bf16 ; O: [B][T][768] bf16
__global__ __launch_bounds__(256) void k_attn(
    const u16* __restrict__ Q, const u16* __restrict__ Kb, const u16* __restrict__ Vt,
    u16* __restrict__ O)
{
    int tid = threadIdx.x, w = tid >> 6, lane = tid & 63;
    int l31 = lane & 31, hi = lane >> 5;
    int bx = blockIdx.x;
    int g = bx / 96, bh = bx - g * 96;          // g in 0..7, bh in 0..95
    int qt = g + 8 * w, q0 = qt * 32;           // wave's q-tile (work-balanced)
    int b = bh / 12, h = bh - b * 12;
    const u16* Qb  = Q  + (size_t)bh * 65536;
    const u16* Kbb = Kb + (size_t)bh * 65536;
    const u16* Vb  = Vt + (size_t)bh * 65536;

    short8 qf[4];
    #pragma unroll
    for (int ch = 0; ch < 4; ch++)
        qf[ch] = *(const short8*)&Qb[(q0 + l31) * 64 + ch * 16 + hi * 8];

    f32x16 o0 = {}, o1 = {};
    float mrun = -INFINITY, lsum = 0.f;
    const float SC = 0.18033688011f;            // 0.125 * log2(e)

    int nit = qt + 1;
    for (int it = 0; it < nit; it++) {
        int kt = it * 32;
        f32x16 s = {};
        #pragma unroll
        for (int ch = 0; ch < 4; ch++) {
            short8 kf = *(const short8*)&Kbb[(kt + l31) * 64 + ch * 16 + hi * 8];
            s = __builtin_amdgcn_mfma_f32_32x32x16_bf16(kf, qf[ch], s, 0, 0, 0);
        }
        float ps[16];
        int qg = q0 + l31;
        #pragma unroll
        for (int r = 0; r < 16; r++) {
            int krow = kt + (r & 3) + 8 * (r >> 2) + 4 * hi;
            ps[r] = (krow <= qg) ? s[r] * SC : -1e30f;
        }
        float t8[8];
        #pragma unroll
        for (int i = 0; i < 8; i++) t8[i] = fmaxf(ps[i], ps[i + 8]);
        float t4a = fmaxf(t8[0], t8[1]), t4b = fmaxf(t8[2], t8[3]);
        float t4c = fmaxf(t8[4], t8[5]), t4d = fmaxf(t8[6], t8[7]);
        float tm = fmaxf(fmaxf(t4a, t4b), fmaxf(t4c, t4d));
        tm = fmaxf(tm, __shfl_xor(tm, 32));
        float mn = fmaxf(mrun, tm);
        float scale = exp2f(mrun - mn);
        mrun = mn;
        float rs = 0.f;
        #pragma unroll
        for (int r = 0; r < 16; r++) { ps[r] = exp2f(ps[r] - mn); rs += ps[r]; }
        rs += __shfl_xor(rs, 32);
        lsum = lsum * scale + rs;
        #pragma unroll
        for (int r = 0; r < 16; r++) { o0[r] *= scale; o1[r] *= scale; }
        u32 c[8], sw[8];
        #pragma unroll
        for (int i = 0; i < 8; i++) c[i] = pk2(ps[2 * i], ps[2 * i + 1]);
        #pragma unroll
        for (int i = 0; i < 8; i++) sw[i] = (u32)__shfl_xor((int)c[i], 32);
        union { u32 u[4]; short8 s8; } pb0, pb1;
        pb0.u[0] = hi ? sw[2] : c[0];
        pb0.u[1] = hi ? sw[3] : c[1];
        pb0.u[2] = hi ? c[2]  : sw[0];
        pb0.u[3] = hi ? c[3]  : sw[1];
        pb1.u[0] = hi ? sw[6] : c[4];
        pb1.u[1] = hi ? sw[7] : c[5];
        pb1.u[2] = hi ? c[6]  : sw[4];
        pb1.u[3] = hi ? c[7]  : sw[5];
        #pragma unroll
        for (int kh = 0; kh < 2; kh++) {
            const short8* pbp = kh ? &pb1.s8 : &pb0.s8;
            short8 vf0 = *(const short8*)&Vb[(size_t)l31 * 1024 + kt + kh * 16 + hi * 8];
            short8 vf1 = *(const short8*)&Vb[(size_t)(32 + l31) * 1024 + kt + kh * 16 + hi * 8];
            o0 = __builtin_amdgcn_mfma_f32_32x32x16_bf16(vf0, *pbp, o0, 0, 0, 0);
            o1 = __builtin_amdgcn_mfma_f32_32x32x16_bf16(vf1, *pbp, o1, 0, 0, 0);
        }
    }

    float inv = 1.0f / lsum;
    int t = q0 + l31;
    size_t base = ((size_t)(b * 1024 + t)) * 768 + h * 64;
    #pragma unroll
    for (int rq = 0; rq < 4; rq++) {
        ushort4 u0, u1;
        u0.x = f2bf(o0[4 * rq + 0] * inv); u0.y = f2bf(o0[4 * rq + 1] * inv);
        u0.z = f2bf(o0[4 * rq + 2] * inv); u0.w = f2bf(o0[4 * rq + 3] * inv);
        u1.x = f2bf(o1[4 * rq + 0] * inv); u1.y = f2bf(o1[4 * rq + 1] * inv);
        u1.z = f2bf(o1[4 * rq + 2] * inv); u1.w = f2bf(o1[4 * rq + 3] * inv);
        *(ushort4*)&O[base + rq * 8 + hi * 4]      = u0;
        *(ushort4*)&O[base + 32 + rq * 8 + hi * 4] = u1;
    }
}

extern "C" void kernel_launch(void* const* d_in, const int* in_sizes, int n_in,
                              void* d_out, int out_size, void* d_ws, size_t ws_size,
                              hipStream_t stream)
{
    const float* x     = (const float*)d_in[0];
    const float* W_qkv = (const float*)d_in[1];
    const float* b_qkv = (const float*)d_in[2];
    const float* W_out = (const float*)d_in[3];
    const float* b_out = (const float*)d_in[4];
    float* out = (float*)d_out;

    char* w = (char*)d_ws;
    u16* xb  = (u16*)w; w += (size_t)8192 * 768 * 2;
    u16* wqt = (u16*)w; w += (size_t)2304 * 768 * 2;
    u16* wot = (u16*)w; w += (size_t)768 * 768 * 2;
    u16* qb  = (u16*)w; w += (size_t)96 * 1024 * 64 * 2;
    u16* kb  = (u16*)w; w += (size_t)96 * 1024 * 64 * 2;
    u16* vt  = (u16*)w; w += (size_t)96 * 64 * 1024 * 2;
    u16* ao  = (u16*)w; w += (size_t)8192 * 768 * 2;

    k_convert<<<dim3(6144), 256, 0, stream>>>(x, xb, 1572864);
    k_transpose_bf<<<dim3(72, 24), dim3(32, 8), 0, stream>>>(W_qkv, wqt, 768, 2304);
    k_transpose_bf<<<dim3(24, 24), dim3(32, 8), 0, stream>>>(W_out, wot, 768, 768);
    k_gemm8p<1><<<dim3(64, 9), 512, 0, stream>>>(xb, wqt, b_qkv, nullptr, qb, kb, vt, 8192, 2304, 768);
    k_attn<<<dim3(768), 256, 0, stream>>>(qb, kb, vt, ao);
    k_gemm8p<0><<<dim3(64, 3), 512, 0, stream>>>(ao, wot, b_out, out, nullptr, nullptr, nullptr, 8192, 768, 768);
}